// Round 5
// baseline (819.552 us; speedup 1.0000x reference)
//
#include <hip/hip_runtime.h>

#define D 128
#define NB_SHIFT 7              // 128 nodes per bucket
#define BKT_NODES 128
#define CAP 16                  // LDS staging entries per bucket
#define PART_BLOCKS 64
#define MAXB 400                // >= B = ceil(50000/128) = 391

typedef __attribute__((ext_vector_type(8))) short bf16x8;
typedef __attribute__((ext_vector_type(4))) float f32x4;

__device__ __forceinline__ short f2bf_rne(float f) {
  unsigned u = __float_as_uint(f);
  unsigned r = u + 0x7fffu + ((u >> 16) & 1u);
  return (short)(r >> 16);
}

__device__ __forceinline__ bf16x8 pack_bf16x8(float4 a, float4 b) {
  bf16x8 h;
  h[0] = f2bf_rne(a.x); h[1] = f2bf_rne(a.y);
  h[2] = f2bf_rne(a.z); h[3] = f2bf_rne(a.w);
  h[4] = f2bf_rne(b.x); h[5] = f2bf_rne(b.y);
  h[6] = f2bf_rne(b.z); h[7] = f2bf_rne(b.w);
  return h;
}

// ---------------- bucket histogram (LDS-privatized) ----------------

__global__ __launch_bounds__(512) void zero_kernel(int* __restrict__ p, int n) {
  int t = blockIdx.x * 512 + threadIdx.x;
  if (t < n) p[t] = 0;
}

__global__ __launch_bounds__(256) void bhist_kernel(const int* __restrict__ row,
                                                    int* __restrict__ gbcnt,
                                                    int E, int B) {
  __shared__ int lh[MAXB];
  for (int i = threadIdx.x; i < B; i += 256) lh[i] = 0;
  __syncthreads();
  const int stride = gridDim.x * 256;
  for (int e = blockIdx.x * 256 + threadIdx.x; e < E; e += stride)
    atomicAdd(&lh[row[e] >> NB_SHIFT], 1);
  __syncthreads();
  for (int i = threadIdx.x; i < B; i += 256)
    if (lh[i]) atomicAdd(&gbcnt[i], lh[i]);
}

// exclusive scan of 8-aligned bucket capacities (1 block)
__global__ __launch_bounds__(512) void bscan_kernel(const int* __restrict__ gbcnt,
                                                    int* __restrict__ bstart,
                                                    int* __restrict__ gcur, int B) {
  __shared__ int lds[512];
  const int t = threadIdx.x;
  int v = (t < B) ? ((gbcnt[t] + 7) & ~7) : 0;
  lds[t] = v;
  __syncthreads();
  for (int off = 1; off < 512; off <<= 1) {
    int u = (t >= off) ? lds[t - off] : 0;
    __syncthreads();
    if (t >= off) lds[t] += u;
    __syncthreads();
  }
  if (t < B) {
    int excl = lds[t] - v;
    bstart[t] = excl;
    gcur[t] = excl;
  }
}

// ---------------- fused: edge partition (blocks 0..63) + GEMM (rest) ----------------
// partition: counting-"sort" edges into 391 row-buckets; LDS staging buffers
// flushed in 8-entry (64B) groups -> contiguous full-line global writes.
// gemm: y = bf16(x @ W^T) with register-resident W frags (R4 kernel, verified).

__global__ __launch_bounds__(256) void part_gemm_kernel(
    const int* __restrict__ erow, const int* __restrict__ ecol,
    const float* __restrict__ ew, int* __restrict__ gcur,
    int2* __restrict__ swcol,
    const float* __restrict__ x, const float* __restrict__ W,
    ushort* __restrict__ y, int E, int N, int B) {
  __shared__ int lcount[MAXB];
  __shared__ int2 lbuf[MAXB][CAP];   // 400*16*8 = 51.2 KB

  if (blockIdx.x < PART_BLOCKS) {
    const int tid = threadIdx.x;
    for (int i = tid; i < B; i += 256) lcount[i] = 0;
    __syncthreads();
    const int chunk = (E + PART_BLOCKS - 1) / PART_BLOCKS;
    const int begin = blockIdx.x * chunk;
    const int end = min(begin + chunk, E);
    for (int base = begin; base < end; base += 256) {
      int e = base + tid;
      if (e < end) {
        int r = erow[e];
        int c = ecol[e];
        float w = ew[e];
        int bkt = r >> NB_SHIFT;
        int rl = r & (BKT_NODES - 1);
        int2 entry = make_int2((rl << 17) | c, __float_as_int(w));
        int pos = atomicAdd(&lcount[bkt], 1);
        if (pos < CAP) lbuf[bkt][pos] = entry;
        else {                                   // ~never (Poisson tail)
          int gp = atomicAdd(&gcur[bkt], 1);
          swcol[gp] = entry;
        }
      }
      __syncthreads();
      for (int b = tid; b < B; b += 256) {       // flush full 8-entry groups
        int c8 = lcount[b]; if (c8 > CAP) c8 = CAP;
        int nfl = c8 & ~7;
        if (nfl) {
          int gp = atomicAdd(&gcur[b], nfl);
          for (int k = 0; k < nfl; ++k) swcol[gp + k] = lbuf[b][k];
          int rem = c8 - nfl;
          for (int k = 0; k < rem; ++k) lbuf[b][k] = lbuf[b][nfl + k];
          lcount[b] = rem;
        } else {
          lcount[b] = c8;
        }
      }
      __syncthreads();
    }
    for (int b = tid; b < B; b += 256) {         // tail flush (<8 entries)
      int c8 = lcount[b]; if (c8 > CAP) c8 = CAP;
      if (c8) {
        int gp = atomicAdd(&gcur[b], c8);
        for (int k = 0; k < c8; ++k) swcol[gp + k] = lbuf[b][k];
      }
    }
  } else {
    // ---- GEMM ----
    const int tid = threadIdx.x;
    const int wave = tid >> 6, lane = tid & 63;
    const int m_half = wave & 1;
    const int n_half = wave >> 1;
    const int l16 = lane & 15, quad = lane >> 4;

    bf16x8 Bf[4][4];
    const float4* W4 = (const float4*)W;
#pragma unroll
    for (int nt = 0; nt < 4; ++nt) {
      int n = n_half * 64 + nt * 16 + l16;
#pragma unroll
      for (int kb = 0; kb < 4; ++kb) {
        int idx = (n * D + kb * 32 + quad * 8) >> 2;
        Bf[nt][kb] = pack_bf16x8(W4[idx], W4[idx + 1]);
      }
    }

    const float4* x4 = (const float4*)x;
    const int ntiles = (N + 63) >> 6;
    const int gstride = gridDim.x - PART_BLOCKS;
    for (int tile = (int)blockIdx.x - PART_BLOCKS; tile < ntiles; tile += gstride) {
      const int row0 = tile * 64 + m_half * 32;
      f32x4 acc[2][4];
#pragma unroll
      for (int mt = 0; mt < 2; ++mt)
#pragma unroll
        for (int nt = 0; nt < 4; ++nt)
          acc[mt][nt] = (f32x4){0.f, 0.f, 0.f, 0.f};

#pragma unroll
      for (int kb = 0; kb < 4; ++kb) {
        const int k0 = kb * 32 + quad * 8;
        int m0 = row0 + l16;      if (m0 > N - 1) m0 = N - 1;
        int m1 = row0 + 16 + l16; if (m1 > N - 1) m1 = N - 1;
        int i0 = (m0 * D + k0) >> 2;
        int i1 = (m1 * D + k0) >> 2;
        float4 p0 = x4[i0], q0 = x4[i0 + 1];
        float4 p1 = x4[i1], q1 = x4[i1 + 1];
        bf16x8 a0 = pack_bf16x8(p0, q0);
        bf16x8 a1 = pack_bf16x8(p1, q1);
#pragma unroll
        for (int nt = 0; nt < 4; ++nt) {
          acc[0][nt] = __builtin_amdgcn_mfma_f32_16x16x32_bf16(a0, Bf[nt][kb], acc[0][nt], 0, 0, 0);
          acc[1][nt] = __builtin_amdgcn_mfma_f32_16x16x32_bf16(a1, Bf[nt][kb], acc[1][nt], 0, 0, 0);
        }
      }

#pragma unroll
      for (int mt = 0; mt < 2; ++mt) {
        int rbase = row0 + mt * 16 + quad * 4;
#pragma unroll
        for (int nt = 0; nt < 4; ++nt) {
          int col = n_half * 64 + nt * 16 + l16;
#pragma unroll
          for (int r = 0; r < 4; ++r) {
            int row = rbase + r;
            if (row < N) y[row * D + col] = (ushort)f2bf_rne(acc[mt][nt][r]);
          }
        }
      }
    }
  }
}

// ---------------- gather: per-bucket LDS accumulation, column-quarter passes ----------------
// block = (bucket, quarter); LDS fp32 acc 128 nodes x 32 cols (16 KB), bias-init.
// y quarter slice = 3.2 MB -> per-XCD L2 resident. Half-wave per edge, 2-deep MLP.

__global__ __launch_bounds__(256) void gather_kernel(
    const ushort* __restrict__ y, const int* __restrict__ bstart,
    const int* __restrict__ gbcnt, const int2* __restrict__ swcol,
    const float* __restrict__ bias, float* __restrict__ out, int N, int B) {
  __shared__ float acc[BKT_NODES * 32];
  const int bkt = blockIdx.x;
  const int q = blockIdx.y;
  const int tid = threadIdx.x;

  for (int i = tid; i < BKT_NODES * 32; i += 256)
    acc[i] = bias[q * 32 + (i & 31)];
  __syncthreads();

  const int s = bstart[bkt];
  const int cnt = gbcnt[bkt];
  const int sub = tid >> 5;   // half-wave id 0..7
  const int l32 = tid & 31;

  for (int j0 = 0; j0 < cnt; j0 += 16) {
    int ja = j0 + sub;
    int jb = ja + 8;
    bool va = ja < cnt, vb = jb < cnt;
    int2 da, db;
    if (va) da = swcol[s + ja];
    if (vb) db = swcol[s + jb];
    float fa = 0.f, fb = 0.f;
    int rla = 0, rlb = 0;
    float wa = 0.f, wb = 0.f;
    if (va) {
      int col = da.x & 0x1FFFF; rla = da.x >> 17; wa = __int_as_float(da.y);
      fa = __uint_as_float(((unsigned)y[col * D + q * 32 + l32]) << 16);
    }
    if (vb) {
      int col = db.x & 0x1FFFF; rlb = db.x >> 17; wb = __int_as_float(db.y);
      fb = __uint_as_float(((unsigned)y[col * D + q * 32 + l32]) << 16);
    }
    if (va) atomicAdd(&acc[rla * 32 + l32], wa * fa);
    if (vb) atomicAdd(&acc[rlb * 32 + l32], wb * fb);
  }
  __syncthreads();

  const int node0 = bkt << NB_SHIFT;
  for (int i = tid; i < BKT_NODES * 32; i += 256) {
    int rl = i >> 5, c = i & 31;
    int node = node0 + rl;
    if (node < N) out[node * D + q * 32 + c] = acc[i];
  }
}

// ---------------- launch ----------------

extern "C" void kernel_launch(void* const* d_in, const int* in_sizes, int n_in,
                              void* d_out, int out_size, void* d_ws, size_t ws_size,
                              hipStream_t stream) {
  const float* x    = (const float*)d_in[0];
  const int*   erow = (const int*)d_in[1];
  const int*   ecol = (const int*)d_in[2];
  const float* ew   = (const float*)d_in[3];
  const float* W    = (const float*)d_in[4];
  const float* b    = (const float*)d_in[5];
  float* out = (float*)d_out;

  const int N = in_sizes[0] / D;
  const int E = in_sizes[1];
  const int B = (N + BKT_NODES - 1) >> NB_SHIFT;

  // workspace
  char* ws = (char*)d_ws;
  ushort* y    = (ushort*)ws;                               // N*D bf16 (12.8 MB)
  int2*  swcol = (int2*)(ws + (size_t)N * D * 2);           // E + slack entries
  int*   gbcnt = (int*)(swcol + E + 8 * MAXB);
  int*   bstart = gbcnt + MAXB;
  int*   gcur   = bstart + MAXB;

  zero_kernel<<<1, 512, 0, stream>>>(gbcnt, B);
  bhist_kernel<<<256, 256, 0, stream>>>(erow, gbcnt, E, B);
  bscan_kernel<<<1, 512, 0, stream>>>(gbcnt, bstart, gcur, B);

  const int ntiles = (N + 63) >> 6;
  part_gemm_kernel<<<PART_BLOCKS + ntiles, 256, 0, stream>>>(
      erow, ecol, ew, gcur, swcol, x, W, y, E, N, B);

  gather_kernel<<<dim3(B, 4), 256, 0, stream>>>(y, bstart, gbcnt, swcol, b, out, N, B);
}

// Round 6
// 172.080 us; speedup vs baseline: 4.7626x; 4.7626x over previous
//
#include <hip/hip_runtime.h>

#define D 128
#define NB_SHIFT 7              // 128 nodes per bucket
#define BKT_NODES 128
#define PB 128                  // partition blocks
#define MAXB 400                // >= B = ceil(50000/128) = 391
#define S2CAP 3072              // stage-2 LDS edge capacity (mean ~2046, >20 sd)

typedef __attribute__((ext_vector_type(8))) short bf16x8;
typedef __attribute__((ext_vector_type(4))) float f32x4;

__device__ __forceinline__ short f2bf_rne(float f) {
  unsigned u = __float_as_uint(f);
  unsigned r = u + 0x7fffu + ((u >> 16) & 1u);
  return (short)(r >> 16);
}

__device__ __forceinline__ bf16x8 pack_bf16x8(float4 a, float4 b) {
  bf16x8 h;
  h[0] = f2bf_rne(a.x); h[1] = f2bf_rne(a.y);
  h[2] = f2bf_rne(a.z); h[3] = f2bf_rne(a.w);
  h[4] = f2bf_rne(b.x); h[5] = f2bf_rne(b.y);
  h[6] = f2bf_rne(b.z); h[7] = f2bf_rne(b.w);
  return h;
}

// ---- pass 1: per-block bucket histogram (LDS), save row + global add ----
__global__ __launch_bounds__(256) void bhist_kernel(const int* __restrict__ erow,
                                                    int* __restrict__ h,
                                                    int* __restrict__ gbcnt,
                                                    int E, int B) {
  __shared__ int lh[MAXB];
  for (int i = threadIdx.x; i < B; i += 256) lh[i] = 0;
  __syncthreads();
  const int chunk = (E + PB - 1) / PB;
  const int begin = blockIdx.x * chunk;
  const int end = min(begin + chunk, E);
  for (int e = begin + threadIdx.x; e < end; e += 256)
    atomicAdd(&lh[erow[e] >> NB_SHIFT], 1);
  __syncthreads();
  for (int i = threadIdx.x; i < B; i += 256) {
    int v = lh[i];
    h[blockIdx.x * MAXB + i] = v;
    if (v) atomicAdd(&gbcnt[i], v);
  }
}

// ---- pass 2: exclusive scan of bucket counts (1 block) ----
__global__ __launch_bounds__(512) void bscan_kernel(const int* __restrict__ gbcnt,
                                                    int* __restrict__ bstart,
                                                    int* __restrict__ gcur, int B) {
  __shared__ int lds[512];
  const int t = threadIdx.x;
  int v = (t < B) ? gbcnt[t] : 0;
  lds[t] = v;
  __syncthreads();
  for (int off = 1; off < 512; off <<= 1) {
    int u = (t >= off) ? lds[t - off] : 0;
    __syncthreads();
    if (t >= off) lds[t] += u;
    __syncthreads();
  }
  if (t < B) {
    int excl = lds[t] - v;
    bstart[t] = excl;
    gcur[t] = excl;
  }
}

// ---- pass 3 fused: bucket partition (blocks 0..PB-1) + GEMM (rest) ----
// partition: block claims contiguous per-(block,bucket) windows (1 atomic per
// bucket), then scatters edges into its own windows -> XCD-local, L2-combined
// full-line writes. entry = ((row&127)<<16 | col, bits(weight)).
// gemm: y = bf16(x @ W^T), register-resident W frags (R4-verified).
__global__ __launch_bounds__(256) void part_gemm_kernel(
    const int* __restrict__ erow, const int* __restrict__ ecol,
    const float* __restrict__ ew, const int* __restrict__ h,
    int* __restrict__ gcur, int2* __restrict__ swcol,
    const float* __restrict__ x, const float* __restrict__ W,
    ushort* __restrict__ y, int E, int N, int B) {
  __shared__ int lcur[MAXB];

  if (blockIdx.x < PB) {
    const int tid = threadIdx.x;
    for (int i = tid; i < B; i += 256) {
      int v = h[blockIdx.x * MAXB + i];
      lcur[i] = v ? atomicAdd(&gcur[i], v) : 0;
    }
    __syncthreads();
    const int chunk = (E + PB - 1) / PB;
    const int begin = blockIdx.x * chunk;
    const int end = min(begin + chunk, E);
    for (int e = begin + tid; e < end; e += 256) {
      int r = erow[e];
      int bkt = r >> NB_SHIFT;
      int rl = r & (BKT_NODES - 1);
      int pos = atomicAdd(&lcur[bkt], 1);
      swcol[pos] = make_int2((rl << 16) | ecol[e], __float_as_int(ew[e]));
    }
  } else {
    // ---- GEMM ----
    const int tid = threadIdx.x;
    const int wave = tid >> 6, lane = tid & 63;
    const int m_half = wave & 1;
    const int n_half = wave >> 1;
    const int l16 = lane & 15, quad = lane >> 4;

    bf16x8 Bf[4][4];
    const float4* W4 = (const float4*)W;
#pragma unroll
    for (int nt = 0; nt < 4; ++nt) {
      int n = n_half * 64 + nt * 16 + l16;
#pragma unroll
      for (int kb = 0; kb < 4; ++kb) {
        int idx = (n * D + kb * 32 + quad * 8) >> 2;
        Bf[nt][kb] = pack_bf16x8(W4[idx], W4[idx + 1]);
      }
    }

    const float4* x4 = (const float4*)x;
    const int ntiles = (N + 63) >> 6;
    const int gstride = gridDim.x - PB;
    for (int tile = (int)blockIdx.x - PB; tile < ntiles; tile += gstride) {
      const int row0 = tile * 64 + m_half * 32;
      f32x4 acc[2][4];
#pragma unroll
      for (int mt = 0; mt < 2; ++mt)
#pragma unroll
        for (int nt = 0; nt < 4; ++nt)
          acc[mt][nt] = (f32x4){0.f, 0.f, 0.f, 0.f};

#pragma unroll
      for (int kb = 0; kb < 4; ++kb) {
        const int k0 = kb * 32 + quad * 8;
        int m0 = row0 + l16;      if (m0 > N - 1) m0 = N - 1;
        int m1 = row0 + 16 + l16; if (m1 > N - 1) m1 = N - 1;
        int i0 = (m0 * D + k0) >> 2;
        int i1 = (m1 * D + k0) >> 2;
        float4 p0 = x4[i0], q0 = x4[i0 + 1];
        float4 p1 = x4[i1], q1 = x4[i1 + 1];
        bf16x8 a0 = pack_bf16x8(p0, q0);
        bf16x8 a1 = pack_bf16x8(p1, q1);
#pragma unroll
        for (int nt = 0; nt < 4; ++nt) {
          acc[0][nt] = __builtin_amdgcn_mfma_f32_16x16x32_bf16(a0, Bf[nt][kb], acc[0][nt], 0, 0, 0);
          acc[1][nt] = __builtin_amdgcn_mfma_f32_16x16x32_bf16(a1, Bf[nt][kb], acc[1][nt], 0, 0, 0);
        }
      }

#pragma unroll
      for (int mt = 0; mt < 2; ++mt) {
        int rbase = row0 + mt * 16 + quad * 4;
#pragma unroll
        for (int nt = 0; nt < 4; ++nt) {
          int col = n_half * 64 + nt * 16 + l16;
#pragma unroll
          for (int r = 0; r < 4; ++r) {
            int row = rbase + r;
            if (row < N) y[row * D + col] = (ushort)f2bf_rne(acc[mt][nt][r]);
          }
        }
      }
    }
  }
}

// ---- pass 4: per-bucket node-granular sort, all in LDS; emits start/cnt ----
__global__ __launch_bounds__(256) void stage2_kernel(
    const int2* __restrict__ swcol, int2* __restrict__ swcol2,
    const int* __restrict__ bstart, const int* __restrict__ gbcnt,
    int* __restrict__ startN, int* __restrict__ cntN, int N) {
  __shared__ int2 ebuf[S2CAP];
  __shared__ int nh[BKT_NODES], sc[BKT_NODES], ncur[BKT_NODES];
  const int b = blockIdx.x, tid = threadIdx.x;
  const int s = bstart[b];
  const int c = gbcnt[b];
  const bool lds_path = (c <= S2CAP);

  if (tid < BKT_NODES) nh[tid] = 0;
  if (lds_path)
    for (int j = tid; j < c; j += 256) ebuf[j] = swcol[s + j];
  __syncthreads();

  if (lds_path) {
    for (int j = tid; j < c; j += 256) atomicAdd(&nh[ebuf[j].x >> 16], 1);
  } else {
    for (int j = tid; j < c; j += 256) atomicAdd(&nh[swcol[s + j].x >> 16], 1);
  }
  __syncthreads();

  if (tid < BKT_NODES) sc[tid] = nh[tid];
  __syncthreads();
  for (int off = 1; off < BKT_NODES; off <<= 1) {
    int v = 0;
    if (tid < BKT_NODES && tid >= off) v = sc[tid - off];
    __syncthreads();
    if (tid < BKT_NODES && tid >= off) sc[tid] += v;
    __syncthreads();
  }
  if (tid < BKT_NODES) {
    int excl = sc[tid] - nh[tid];
    ncur[tid] = excl;
    int node = (b << NB_SHIFT) + tid;
    if (node < N) { startN[node] = s + excl; cntN[node] = nh[tid]; }
  }
  __syncthreads();

  if (lds_path) {
    for (int j = tid; j < c; j += 256) {
      int2 en = ebuf[j];
      int pos = atomicAdd(&ncur[en.x >> 16], 1);
      swcol2[s + pos] = en;
    }
  } else {
    for (int j = tid; j < c; j += 256) {
      int2 en = swcol[s + j];
      int pos = atomicAdd(&ncur[en.x >> 16], 1);
      swcol2[s + pos] = en;
    }
  }
}

// ---- gather: out[i] = b + sum_j w_j * y[col_j]  (R4-verified shape) ----
__global__ __launch_bounds__(256) void gather_agg_kernel(
    const ushort* __restrict__ y, const int* __restrict__ startN,
    const int* __restrict__ cntN, const int2* __restrict__ swcol2,
    const float* __restrict__ bias, float* __restrict__ out, int N) {
  const int node = blockIdx.x * 4 + (threadIdx.x >> 6);
  const int lane = threadIdx.x & 63;
  if (node >= N) return;

  const unsigned* __restrict__ y1 = (const unsigned*)y;
  float2 acc = ((const float2*)bias)[lane];

  const int s = startN[node];
  const int t = s + cntN[node];
#pragma unroll 4
  for (int j = s; j < t; ++j) {
    int2 cw = swcol2[j];                 // wave-uniform 8B broadcast
    int col = cw.x & 0xFFFF;
    float wg = __int_as_float(cw.y);
    unsigned v = y1[col * 64 + lane];    // 256 B/edge coalesced gather
    float f0 = __uint_as_float(v << 16);
    float f1 = __uint_as_float(v & 0xffff0000u);
    acc.x += wg * f0;
    acc.y += wg * f1;
  }
  ((float2*)out)[node * 64 + lane] = acc;
}

// ---- launch ----
extern "C" void kernel_launch(void* const* d_in, const int* in_sizes, int n_in,
                              void* d_out, int out_size, void* d_ws, size_t ws_size,
                              hipStream_t stream) {
  const float* x    = (const float*)d_in[0];
  const int*   erow = (const int*)d_in[1];
  const int*   ecol = (const int*)d_in[2];
  const float* ew   = (const float*)d_in[3];
  const float* W    = (const float*)d_in[4];
  const float* b    = (const float*)d_in[5];
  float* out = (float*)d_out;

  const int N = in_sizes[0] / D;
  const int E = in_sizes[1];
  const int B = (N + BKT_NODES - 1) >> NB_SHIFT;

  // workspace layout
  char* ws = (char*)d_ws;
  ushort* y      = (ushort*)ws;                              // N*D bf16 (12.8 MB)
  int2*   swcol  = (int2*)(ws + (size_t)N * D * 2);          // E entries
  int2*   swcol2 = swcol + E;                                // E entries
  int*    h      = (int*)(swcol2 + E);                       // PB*MAXB
  int*    gbcnt  = h + PB * MAXB;                            // MAXB
  int*    bstart = gbcnt + MAXB;                             // MAXB
  int*    gcur   = bstart + MAXB;                            // MAXB
  int*    startN = gcur + MAXB;                              // N
  int*    cntN   = startN + N;                               // N

  hipMemsetAsync(gbcnt, 0, (size_t)B * sizeof(int), stream);

  bhist_kernel<<<PB, 256, 0, stream>>>(erow, h, gbcnt, E, B);
  bscan_kernel<<<1, 512, 0, stream>>>(gbcnt, bstart, gcur, B);

  const int ntiles = (N + 63) >> 6;
  part_gemm_kernel<<<PB + ntiles, 256, 0, stream>>>(
      erow, ecol, ew, h, gcur, swcol, x, W, y, E, N, B);

  stage2_kernel<<<B, 256, 0, stream>>>(swcol, swcol2, bstart, gbcnt, startN, cntN, N);

  gather_agg_kernel<<<(N + 3) / 4, 256, 0, stream>>>(y, startN, cntN, swcol2, b, out, N);
}